// Round 2
// baseline (128.200 us; speedup 1.0000x reference)
//
#include <hip/hip_runtime.h>

// Affinity: M[b, i, j] (16 x 256 x 256) where
//   off-diag (a=i>>4, c=i&15, p=j>>4, q=j&15; a<p, c<q, both edges present):
//     M = P1[a,c] + P2[p,c] + P2[a,q] + P1[p,q]
//   diag: += Mp[i]
// with P_l = F_src^T relu(lam_l + lam_l^T) F_tgt  (16x16 per batch),
//      Mp  = U_src^T U_tgt.
// Single fused kernel: grid 32 = (batch, row-half), block 256.

__device__ __forceinline__ int edge_idx(int a, int p) {
    // strict upper triangle of 16x16, row-major (triu_indices(16, k=1))
    return (a * (31 - a)) / 2 + (p - a - 1);
}

#define LTS 130   // sLT padded stride (2v+i bank pattern -> <=2-way, free)
#define TS  17    // sT/sTp/sP padded stride (17 odd -> distinct banks)

__global__ __launch_bounds__(256) void kAll(
    const int* __restrict__ Asrc, const int* __restrict__ Atgt,
    const float* __restrict__ Fsrc, const float* __restrict__ Ftgt,
    const float* __restrict__ Usrc, const float* __restrict__ Utgt,
    const float* __restrict__ lam1, const float* __restrict__ lam2,
    float* __restrict__ out)
{
    __shared__ float sFt[2048];        // F_tgt[b]: [d=128][v=16]
    __shared__ float sFs[2048];        // F_src[b]: [d=128][u=16]
    __shared__ float sLT[16 * LTS];    // lam column chunk, transposed
    __shared__ float sTp[128 * TS];    // h=1 partial accumulators
    __shared__ float sT1[128 * TS];    // T1[i][v]
    __shared__ float sT2[128 * TS];    // T2[i][v]
    __shared__ float sP1[16 * TS];
    __shared__ float sP2[16 * TS];
    __shared__ float sMp[256];
    __shared__ int   smask[120];

    const int blk  = blockIdx.x;
    const int b    = blk >> 1;
    const int half = blk & 1;          // which 128 output rows this block fills
    const int t    = threadIdx.x;

    // ---- stage F tiles + edge mask -------------------------------------
    const float* Ft = Ftgt + b * 2048;
    const float* Fs = Fsrc + b * 2048;
    for (int k = t; k < 2048; k += 256) { sFt[k] = Ft[k]; sFs[k] = Fs[k]; }
    if (t < 120) smask[t] = (Asrc[b * 120 + t] > 0) && (Atgt[b * 120 + t] > 0);

    const int i = t & 127;             // row of T this thread owns
    const int h = t >> 7;              // j-half (wave-uniform)

    // ---- T phase: T_l[i][v] = sum_j relu(lam[i,j]+lam[j,i]) * Ft[j][v] --
    for (int lsel = 0; lsel < 2; ++lsel) {
        const float* lam = lsel ? lam2 : lam1;
        float acc[16];
#pragma unroll
        for (int v = 0; v < 16; ++v) acc[v] = 0.f;

        for (int j0 = 0; j0 < 128; j0 += 16) {
            __syncthreads();   // protect sLT reuse
            // stage columns j0..j0+15 of lam, transposed: sLT[jj][i] = lam[i][j0+jj]
#pragma unroll
            for (int it = 0; it < 8; ++it) {
                const int k = t + it * 256;
                sLT[(k & 15) * LTS + (k >> 4)] = lam[(k >> 4) * 128 + j0 + (k & 15)];
            }
            __syncthreads();
#pragma unroll
            for (int jj = 0; jj < 8; ++jj) {
                const int jl = h * 8 + jj;
                const int j  = j0 + jl;
                float w = sLT[jl * LTS + i] + lam[j * 128 + i]; // lam[i,j] + lam[j,i]
                w = fmaxf(w, 0.f);
                const float4* fr = (const float4*)(sFt + (j << 4));
                const float4 f0 = fr[0], f1 = fr[1], f2 = fr[2], f3 = fr[3];
                acc[0]  = fmaf(w, f0.x, acc[0]);
                acc[1]  = fmaf(w, f0.y, acc[1]);
                acc[2]  = fmaf(w, f0.z, acc[2]);
                acc[3]  = fmaf(w, f0.w, acc[3]);
                acc[4]  = fmaf(w, f1.x, acc[4]);
                acc[5]  = fmaf(w, f1.y, acc[5]);
                acc[6]  = fmaf(w, f1.z, acc[6]);
                acc[7]  = fmaf(w, f1.w, acc[7]);
                acc[8]  = fmaf(w, f2.x, acc[8]);
                acc[9]  = fmaf(w, f2.y, acc[9]);
                acc[10] = fmaf(w, f2.z, acc[10]);
                acc[11] = fmaf(w, f2.w, acc[11]);
                acc[12] = fmaf(w, f3.x, acc[12]);
                acc[13] = fmaf(w, f3.y, acc[13]);
                acc[14] = fmaf(w, f3.z, acc[14]);
                acc[15] = fmaf(w, f3.w, acc[15]);
            }
        }
        __syncthreads();
        if (h == 1) {
#pragma unroll
            for (int v = 0; v < 16; ++v) sTp[i * TS + v] = acc[v];
        }
        __syncthreads();
        float* sT = lsel ? sT2 : sT1;
        if (h == 0) {
#pragma unroll
            for (int v = 0; v < 16; ++v) sT[i * TS + v] = acc[v] + sTp[i * TS + v];
        }
    }
    __syncthreads();

    // ---- P phase: P_l[u][v] = sum_d Fs[d][u] * T_l[d][v];  Mp[u][v] ------
    {
        const int u = t >> 4, v = t & 15;
        float p1 = 0.f, p2 = 0.f;
#pragma unroll 8
        for (int d = 0; d < 128; ++d) {
            const float fs = sFs[(d << 4) | u];
            p1 = fmaf(fs, sT1[d * TS + v], p1);
            p2 = fmaf(fs, sT2[d * TS + v], p2);
        }
        const float* Us = Usrc + b * 256;
        const float* Ut = Utgt + b * 256;
        float mp = 0.f;
#pragma unroll
        for (int d = 0; d < 16; ++d)
            mp = fmaf(Us[(d << 4) | u], Ut[(d << 4) | v], mp);
        sP1[u * TS + v] = p1;
        sP2[u * TS + v] = p2;
        sMp[t] = mp;            // sMp[(u<<4)|v]
    }
    __syncthreads();

    // ---- fill phase: rows [half*128, half*128+128), coalesced float4 ----
    const int rbase = (half << 7) + (t >> 6);
    const int j0c   = (t & 63) << 2;
    const int p     = j0c >> 4;
    float* outB = out + ((size_t)b << 16);
#pragma unroll 4
    for (int rr = 0; rr < 32; ++rr) {
        const int r = rbase + (rr << 2);
        const int a = r >> 4, c = r & 15;
        const bool condT = (a < p) && (smask[edge_idx(a, p)] != 0);
        const float cpart = sP1[a * TS + c] + sP2[p * TS + c];
        float4 vec;
        float* vv = (float*)&vec;
#pragma unroll
        for (int s = 0; s < 4; ++s) {
            const int j = j0c + s, q = j & 15;
            float x = 0.f;
            if (condT && (c < q) && (smask[edge_idx(c, q)] != 0))
                x = cpart + sP2[a * TS + q] + sP1[p * TS + q];
            if (r == j) x += sMp[r];
            vv[s] = x;
        }
        *(float4*)(outB + (r << 8) + j0c) = vec;
    }
}

extern "C" void kernel_launch(void* const* d_in, const int* in_sizes, int n_in,
                              void* d_out, int out_size, void* d_ws, size_t ws_size,
                              hipStream_t stream) {
    const int*   A_src = (const int*)d_in[0];
    const int*   A_tgt = (const int*)d_in[1];
    const float* F_src = (const float*)d_in[2];
    const float* F_tgt = (const float*)d_in[3];
    const float* U_src = (const float*)d_in[4];
    const float* U_tgt = (const float*)d_in[5];
    const float* lam1  = (const float*)d_in[6];
    const float* lam2  = (const float*)d_in[7];
    float* out = (float*)d_out;

    kAll<<<32, 256, 0, stream>>>(A_src, A_tgt, F_src, F_tgt,
                                 U_src, U_tgt, lam1, lam2, out);
}

// Round 3
// 80.144 us; speedup vs baseline: 1.5996x; 1.5996x over previous
//
#include <hip/hip_runtime.h>

// M[b,i,j] (16 x 256 x 256):
//   a=i>>4, c=i&15, p=j>>4, q=j&15
//   off-diag (a<p, c<q, edge(a,p) and edge(c,q) present in BOTH graphs):
//     M = P1[a,c] + P2[p,c] + P2[a,q] + P1[p,q]
//   diag (i==j): += Mp[a,c]
// P_l = F_src^T relu(lam_l+lam_l^T) F_tgt  (16x16/batch), Mp = U_src^T U_tgt.
//
// kA: T_l = relu(lam_l+lam_l^T) F_tgt  -> ws   (grid 128, short LDS-only loop)
// kB: P tables (redundant per block) + output fill (grid 256, float4 stores)

#define LS 132   // lam row/col LDS stride (4*il+j bank pattern -> conflict-free)
#define TS 17    // P-table stride (17p+c distinct banks for p,c in [0,16))

__device__ __forceinline__ int edge_idx(int a, int p) {
    // strict upper triangle of 16x16, row-major (triu_indices(16, k=1))
    return (a * (31 - a)) / 2 + (p - a - 1);
}

// ---------------------------------------------------------------------------
// kA: T_l[b][i][v] = sum_j relu(lam_l[i][j]+lam_l[j][i]) * Ftgt[b][j][v]
// grid 128: b = blk>>3, i0 = (blk&7)*16 ; block 256: il = t>>4, v = t&15
// ws layout: T[b][lsel][i][v] at ((b*2+lsel)*128 + i)*16 + v
// ---------------------------------------------------------------------------
__global__ __launch_bounds__(256) void kA(
    const float* __restrict__ Ftgt,
    const float* __restrict__ lam1, const float* __restrict__ lam2,
    float* __restrict__ ws)
{
    __shared__ float sRow1[16 * LS], sCol1[16 * LS];
    __shared__ float sRow2[16 * LS], sCol2[16 * LS];
    __shared__ float sFt[2048];

    const int blk = blockIdx.x;
    const int b   = blk >> 3;
    const int i0  = (blk & 7) << 4;
    const int t   = threadIdx.x;

    // rows: sRowX[il*LS + j] = lamX[(i0+il)*128 + j]  (float4, coalesced)
    {
        const float4* r1 = (const float4*)(lam1 + i0 * 128);
        const float4* r2 = (const float4*)(lam2 + i0 * 128);
#pragma unroll
        for (int it = 0; it < 2; ++it) {
            const int k = t + it * 256;           // [0,512) float4s
            const int il = k >> 5, j4 = k & 31;
            *(float4*)(&sRow1[il * LS + j4 * 4]) = r1[il * 32 + j4];
            *(float4*)(&sRow2[il * LS + j4 * 4]) = r2[il * 32 + j4];
        }
        // cols: sColX[il*LS + j] = lamX[j*128 + i0+il]  (strided gather, L2-hot)
#pragma unroll
        for (int it = 0; it < 8; ++it) {
            const int k = t + it * 256;           // [0,2048)
            const int il = k & 15, j = k >> 4;
            sCol1[il * LS + j] = lam1[j * 128 + i0 + il];
            sCol2[il * LS + j] = lam2[j * 128 + i0 + il];
        }
        const float4* f = (const float4*)(Ftgt + b * 2048);
        ((float4*)sFt)[t] = f[t];
        ((float4*)sFt)[t + 256] = f[t + 256];
    }
    __syncthreads();

    const int il = t >> 4, v = t & 15;
    float a1 = 0.f, a2 = 0.f;
#pragma unroll 8
    for (int j = 0; j < 128; ++j) {
        const float w1 = fmaxf(sRow1[il * LS + j] + sCol1[il * LS + j], 0.f);
        const float w2 = fmaxf(sRow2[il * LS + j] + sCol2[il * LS + j], 0.f);
        const float fv = sFt[(j << 4) | v];
        a1 = fmaf(w1, fv, a1);
        a2 = fmaf(w2, fv, a2);
    }
    const int i = i0 + il;
    ws[((b * 2 + 0) * 128 + i) * 16 + v] = a1;
    ws[((b * 2 + 1) * 128 + i) * 16 + v] = a2;
}

// ---------------------------------------------------------------------------
// kB: per-block P1/P2/Mp tables (redundant across the 16 row-groups of a
// batch — cheap, fully parallel), then fill 16 output rows.
// grid 256: b = blk>>4, a = blk&15 ; block 256.
// ---------------------------------------------------------------------------
__global__ __launch_bounds__(256) void kB(
    const int* __restrict__ Asrc, const int* __restrict__ Atgt,
    const float* __restrict__ Fsrc,
    const float* __restrict__ Usrc, const float* __restrict__ Utgt,
    const float* __restrict__ ws, float* __restrict__ out)
{
    __shared__ float sT1[2048], sT2[2048], sFs[2048];
    __shared__ float sU[512];                     // Us | Ut
    __shared__ float sP1[16 * TS], sP2[16 * TS], sMp[256];
    __shared__ int   smask[120];

    const int blk = blockIdx.x;
    const int b   = blk >> 4;
    const int a   = blk & 15;                     // tgt node of this row group
    const int t   = threadIdx.x;

    // ---- stage (all float4, coalesced; ws/inputs L2-hot across 16 blocks/b)
    {
        const float4* T1g = (const float4*)(ws + (b * 2 + 0) * 2048);
        const float4* T2g = (const float4*)(ws + (b * 2 + 1) * 2048);
        const float4* Fg  = (const float4*)(Fsrc + b * 2048);
        ((float4*)sT1)[t] = T1g[t];  ((float4*)sT1)[t + 256] = T1g[t + 256];
        ((float4*)sT2)[t] = T2g[t];  ((float4*)sT2)[t + 256] = T2g[t + 256];
        ((float4*)sFs)[t] = Fg[t];   ((float4*)sFs)[t + 256] = Fg[t + 256];
        if (t < 64)       ((float4*)sU)[t]      = ((const float4*)(Usrc + b * 256))[t];
        else if (t < 128) ((float4*)sU)[t]      = ((const float4*)(Utgt + b * 256))[t - 64];
        if (t < 120) smask[t] = (Asrc[b * 120 + t] > 0) && (Atgt[b * 120 + t] > 0);
    }
    __syncthreads();

    // ---- tables: P_l[u][v] = sum_d Fs[d][u]*T_l[d][v]; Mp[u][v]
    {
        const int u = t >> 4, v = t & 15;
        float p1 = 0.f, p2 = 0.f;
#pragma unroll 8
        for (int d = 0; d < 128; ++d) {
            const float fs = sFs[(d << 4) | u];
            p1 = fmaf(fs, sT1[(d << 4) | v], p1);
            p2 = fmaf(fs, sT2[(d << 4) | v], p2);
        }
        float mp = 0.f;
#pragma unroll
        for (int d = 0; d < 16; ++d)
            mp = fmaf(sU[(d << 4) | u], sU[256 + ((d << 4) | v)], mp);
        sP1[u * TS + v] = p1;
        sP2[u * TS + v] = p2;
        sMp[t] = mp;                               // Mp[u][v] at (u<<4)|v
    }
    __syncthreads();

    // ---- fill rows r = a*16 + c, c in [0,16); coalesced float4 stores
    const int j0 = (t & 63) << 2;                  // column base
    const int p  = j0 >> 4;
    const bool condA = (a < p) && (smask[edge_idx(a, p)] != 0);
    float* outR = out + ((size_t)b << 16) + (a << 12);
#pragma unroll
    for (int rr = 0; rr < 4; ++rr) {
        const int c = (t >> 6) + (rr << 2);
        const int r = (a << 4) | c;
        const float cpart = sP1[a * TS + c] + sP2[p * TS + c];
        float4 vec;
        float* vv = (float*)&vec;
#pragma unroll
        for (int s = 0; s < 4; ++s) {
            const int j = j0 + s, q = j & 15;
            float x = 0.f;
            if (condA && (c < q) && (smask[edge_idx(c, q)] != 0))
                x = cpart + sP2[a * TS + q] + sP1[p * TS + q];
            if (r == j) x += sMp[r];
            vv[s] = x;
        }
        *(float4*)(outR + (c << 8) + j0) = vec;
    }
}

extern "C" void kernel_launch(void* const* d_in, const int* in_sizes, int n_in,
                              void* d_out, int out_size, void* d_ws, size_t ws_size,
                              hipStream_t stream) {
    const int*   A_src = (const int*)d_in[0];
    const int*   A_tgt = (const int*)d_in[1];
    const float* F_src = (const float*)d_in[2];
    const float* F_tgt = (const float*)d_in[3];
    const float* U_src = (const float*)d_in[4];
    const float* U_tgt = (const float*)d_in[5];
    const float* lam1  = (const float*)d_in[6];
    const float* lam2  = (const float*)d_in[7];
    float* out = (float*)d_out;
    float* ws  = (float*)d_ws;   // 65536 floats = 256 KB used

    kA<<<128, 256, 0, stream>>>(F_tgt, lam1, lam2, ws);
    kB<<<256, 256, 0, stream>>>(A_src, A_tgt, F_src, U_src, U_tgt, ws, out);
}

// Round 4
// 77.754 us; speedup vs baseline: 1.6488x; 1.0307x over previous
//
#include <hip/hip_runtime.h>

// M[b,i,j] (16 x 256 x 256):
//   a=i>>4, c=i&15, p=j>>4, q=j&15
//   off-diag (a<p, c<q, edge(a,p) and edge(c,q) present in BOTH graphs):
//     M = P1[a,c] + P2[p,c] + P2[a,q] + P1[p,q]
//   diag (i==j): += Mp[a,c]
// P_l = F_src^T relu(lam_l+lam_l^T) F_tgt  (16x16/batch), Mp = U_src^T U_tgt.
//
// kA: T_l = relu(lam_l+lam_l^T) F_tgt -> ws. grid 256 = (b, lsel, i-slice):
//     1 block/CU, single barrier, float4 LDS inner loop.
// kB: P tables (redundant per block, cheap) + output fill. grid 256 = (b, a).

#define LS 132   // sRow/sCol stride: il*132+j -> (132il+j)%32 pattern, j%4 vec-aligned
#define TS 17    // P-table stride

__device__ __forceinline__ int edge_idx(int a, int p) {
    // strict upper triangle of 16x16, row-major (triu_indices(16, k=1))
    return (a * (31 - a)) / 2 + (p - a - 1);
}

// ---------------------------------------------------------------------------
// kA: T[b][lsel][i][v] = sum_j relu(lam[i][j]+lam[j][i]) * Ftgt[b][j][v]
// grid 256: b = blk>>4, lsel = (blk>>3)&1, i0 = (blk&7)*16
// block 256: il = t>>4, v = t&15
// ws: T at ((b*2+lsel)*128 + i)*16 + v
// ---------------------------------------------------------------------------
__global__ __launch_bounds__(256) void kA(
    const float* __restrict__ Ftgt,
    const float* __restrict__ lam1, const float* __restrict__ lam2,
    float* __restrict__ ws)
{
    __shared__ float sRow[16 * LS];
    __shared__ float sCol[16 * LS];
    __shared__ float sFt[2048];

    const int blk  = blockIdx.x;
    const int b    = blk >> 4;
    const int lsel = (blk >> 3) & 1;
    const int i0   = (blk & 7) << 4;
    const int t    = threadIdx.x;

    const float* lam = lsel ? lam2 : lam1;

    // rows (coalesced float4): sRow[il*LS + j] = lam[(i0+il)*128 + j]
    {
        const float4* rp = (const float4*)(lam + i0 * 128);
#pragma unroll
        for (int it = 0; it < 2; ++it) {
            const int k  = t + it * 256;        // [0,512) float4s
            const int il = k >> 5, j4 = k & 31;
            *(float4*)(&sRow[il * LS + j4 * 4]) = rp[il * 32 + j4];
        }
        // cols (transposed gather, 64B-contiguous per 16 lanes, L2-hot):
        //   sCol[il*LS + j] = lam[j*128 + i0 + il]
#pragma unroll
        for (int it = 0; it < 8; ++it) {
            const int k  = t + it * 256;        // [0,2048)
            const int il = k & 15, j = k >> 4;
            sCol[il * LS + j] = lam[j * 128 + i0 + il];
        }
        const float4* f = (const float4*)(Ftgt + b * 2048);
        ((float4*)sFt)[t]       = f[t];
        ((float4*)sFt)[t + 256] = f[t + 256];
    }
    __syncthreads();

    const int il = t >> 4, v = t & 15;
    float acc = 0.f;
#pragma unroll 8
    for (int j0 = 0; j0 < 128; j0 += 4) {
        const float4 r = *(const float4*)(&sRow[il * LS + j0]);
        const float4 c = *(const float4*)(&sCol[il * LS + j0]);
        acc = fmaf(fmaxf(r.x + c.x, 0.f), sFt[((j0 + 0) << 4) | v], acc);
        acc = fmaf(fmaxf(r.y + c.y, 0.f), sFt[((j0 + 1) << 4) | v], acc);
        acc = fmaf(fmaxf(r.z + c.z, 0.f), sFt[((j0 + 2) << 4) | v], acc);
        acc = fmaf(fmaxf(r.w + c.w, 0.f), sFt[((j0 + 3) << 4) | v], acc);
    }
    ws[((b * 2 + lsel) * 128 + i0 + il) * 16 + v] = acc;
}

// ---------------------------------------------------------------------------
// kB: per-block P1/P2/Mp tables (redundant across the 16 row-groups of a
// batch — cheap, fully parallel), then fill 16 output rows.
// grid 256: b = blk>>4, a = blk&15 ; block 256.
// ---------------------------------------------------------------------------
__global__ __launch_bounds__(256) void kB(
    const int* __restrict__ Asrc, const int* __restrict__ Atgt,
    const float* __restrict__ Fsrc,
    const float* __restrict__ Usrc, const float* __restrict__ Utgt,
    const float* __restrict__ ws, float* __restrict__ out)
{
    __shared__ float sT1[2048], sT2[2048], sFs[2048];
    __shared__ float sU[512];                     // Us | Ut
    __shared__ float sP1[16 * TS], sP2[16 * TS], sMp[256];
    __shared__ int   smask[120];

    const int blk = blockIdx.x;
    const int b   = blk >> 4;
    const int a   = blk & 15;                     // tgt node of this row group
    const int t   = threadIdx.x;

    // ---- stage (all float4, coalesced; ws/inputs L2-hot across 16 blocks/b)
    {
        const float4* T1g = (const float4*)(ws + (b * 2 + 0) * 2048);
        const float4* T2g = (const float4*)(ws + (b * 2 + 1) * 2048);
        const float4* Fg  = (const float4*)(Fsrc + b * 2048);
        ((float4*)sT1)[t] = T1g[t];  ((float4*)sT1)[t + 256] = T1g[t + 256];
        ((float4*)sT2)[t] = T2g[t];  ((float4*)sT2)[t + 256] = T2g[t + 256];
        ((float4*)sFs)[t] = Fg[t];   ((float4*)sFs)[t + 256] = Fg[t + 256];
        if (t < 64)       ((float4*)sU)[t] = ((const float4*)(Usrc + b * 256))[t];
        else if (t < 128) ((float4*)sU)[t] = ((const float4*)(Utgt + b * 256))[t - 64];
        if (t < 120) smask[t] = (Asrc[b * 120 + t] > 0) && (Atgt[b * 120 + t] > 0);
    }
    __syncthreads();

    // ---- tables: P_l[u][v] = sum_d Fs[d][u]*T_l[d][v]; Mp[u][v]
    {
        const int u = t >> 4, v = t & 15;
        float p1 = 0.f, p2 = 0.f;
#pragma unroll 8
        for (int d = 0; d < 128; ++d) {
            const float fs = sFs[(d << 4) | u];
            p1 = fmaf(fs, sT1[(d << 4) | v], p1);
            p2 = fmaf(fs, sT2[(d << 4) | v], p2);
        }
        float mp = 0.f;
#pragma unroll
        for (int d = 0; d < 16; ++d)
            mp = fmaf(sU[(d << 4) | u], sU[256 + ((d << 4) | v)], mp);
        sP1[u * TS + v] = p1;
        sP2[u * TS + v] = p2;
        sMp[t] = mp;                               // Mp[u][v] at (u<<4)|v
    }
    __syncthreads();

    // ---- fill rows r = a*16 + c, c in [0,16); coalesced float4 stores
    const int j0 = (t & 63) << 2;                  // column base
    const int p  = j0 >> 4;
    const bool condA = (a < p) && (smask[edge_idx(a, p)] != 0);
    float* outR = out + ((size_t)b << 16) + (a << 12);
#pragma unroll
    for (int rr = 0; rr < 4; ++rr) {
        const int c = (t >> 6) + (rr << 2);
        const int r = (a << 4) | c;
        const float cpart = sP1[a * TS + c] + sP2[p * TS + c];
        float4 vec;
        float* vv = (float*)&vec;
#pragma unroll
        for (int s = 0; s < 4; ++s) {
            const int j = j0 + s, q = j & 15;
            float x = 0.f;
            if (condA && (c < q) && (smask[edge_idx(c, q)] != 0))
                x = cpart + sP2[a * TS + q] + sP1[p * TS + q];
            if (r == j) x += sMp[r];
            vv[s] = x;
        }
        *(float4*)(outR + (c << 8) + j0) = vec;
    }
}

extern "C" void kernel_launch(void* const* d_in, const int* in_sizes, int n_in,
                              void* d_out, int out_size, void* d_ws, size_t ws_size,
                              hipStream_t stream) {
    const int*   A_src = (const int*)d_in[0];
    const int*   A_tgt = (const int*)d_in[1];
    const float* F_src = (const float*)d_in[2];
    const float* F_tgt = (const float*)d_in[3];
    const float* U_src = (const float*)d_in[4];
    const float* U_tgt = (const float*)d_in[5];
    const float* lam1  = (const float*)d_in[6];
    const float* lam2  = (const float*)d_in[7];
    float* out = (float*)d_out;
    float* ws  = (float*)d_ws;   // 65536 floats = 256 KB used

    kA<<<256, 256, 0, stream>>>(F_tgt, lam1, lam2, ws);
    kB<<<256, 256, 0, stream>>>(A_src, A_tgt, F_src, U_src, U_tgt, ws, out);
}